// Round 2
// baseline (132.420 us; speedup 1.0000x reference)
//
#include <hip/hip_runtime.h>
#include <hip/hip_bf16.h>

// SubnetGate = gathered grouped GEMM (B=16384, K=512, N=512, E=8, col 0).
// R4 vs R3:
//  - prep: scatter rebuilt as 8 expert-blocks with ballot+prefix compaction
//    -> ZERO global atomics (R3 had 512 contended cross-XCD atomicAdds on one
//    line = suspected ~75us critical-path cost). counts via plain store ->
//    memset launch removed (2 launches total).
//  - prep: x pre-converted to bf16 (xg, 16MB in ws) -> gemm A volume halves,
//    per-expert x slice (2MB) becomes L2-resident per XCD.
//  - gemm: BM 128 (W-tile volume halves), 4-deep B pipeline: global_load_lds
//    staged 3-ahead, raw s_barrier + counted vmcnt(12) (never drains), A in
//    registers (per-lane 16B bf16 gather), setprio around MFMA cluster.
//  - runtime ws_size check: if xg doesn't fit, f32-gather fallback path.
//
// ws layout:
//   [0,      32)       int counts[8]
//   [4096,   528384)   int rowlist[8][16384]
//   [528384, 4722688)  ushort Wtile[8][4 nt][8 kt][128n x 64k bf16, swizzled]
//   [4722688, 21499904) ushort xg[16384][512]   (bf16 copy of x, optional)

#define NROWS   16384
#define KDIM    512
#define NDIM    512
#define NEXP    8
#define BM      128
#define BN      128
#define BK      64
#define NT_PER  4
#define KT_PER  8
#define TILE_ELEMS (BN * BK)          // 8192 bf16 = 16KB
#define WS_ROWLIST_OFF 4096
#define WS_WT_OFF      (4096 + NEXP * NROWS * 4)
#define WS_XG_OFF      (WS_WT_OFF + (size_t)NEXP * NT_PER * KT_PER * TILE_ELEMS * 2)
#define WS_NEEDED      (WS_XG_OFF + (size_t)NROWS * KDIM * 2)

typedef __bf16        bf16x8 __attribute__((ext_vector_type(8)));
typedef float         f32x4  __attribute__((ext_vector_type(4)));
typedef unsigned int  u32x4  __attribute__((ext_vector_type(4)));

__device__ __forceinline__ unsigned int f2bf_u(float f) {
    unsigned int u = __builtin_bit_cast(unsigned int, f);
    return (u + 0x7FFFu + ((u >> 16) & 1u)) >> 16;   // RNE f32->bf16
}

__device__ __forceinline__ void gl_lds16(const void* g, void* l) {
    __builtin_amdgcn_global_load_lds(
        (const __attribute__((address_space(1))) unsigned int*)g,
        (__attribute__((address_space(3))) unsigned int*)l, 16, 0, 0);
}

__device__ __forceinline__ bf16x8 pack_bf8(f32x4 lo, f32x4 hi) {
    u32x4 w;
    w.x = f2bf_u(lo.x) | (f2bf_u(lo.y) << 16);
    w.y = f2bf_u(lo.z) | (f2bf_u(lo.w) << 16);
    w.z = f2bf_u(hi.x) | (f2bf_u(hi.y) << 16);
    w.w = f2bf_u(hi.z) | (f2bf_u(hi.w) << 16);
    return __builtin_bit_cast(bf16x8, w);
}

// blocks [0,8): scatter — block e scans ALL groups, ballot+prefix compaction,
//   no atomics at all; writes counts[e] with a plain store at the end.
// blocks [8,1032): build one quarter (32 n-cols) of a 16KB swizzled B-tile
//   (identical layout to R3: granule (n,g) -> byte off n*128 + (g^(n&7))*16).
// blocks [1032,3080): x f32->bf16 convert into xg (only when xg enabled).
__global__ void prep_kernel(const float* __restrict__ W,
                            const float* __restrict__ x,
                            const int* __restrict__ groups,
                            int* __restrict__ counts,
                            int* __restrict__ rowlist,
                            unsigned short* __restrict__ Wtile,
                            unsigned short* __restrict__ xg) {
    const int bid = blockIdx.x;
    const int tid = threadIdx.x;

    if (bid < 8) {
        // ---- scatter: expert e = bid, 16 iters x (256 thr x 4 rows)
        __shared__ int wcnt_s[4];
        __shared__ int woff_s[4];
        __shared__ int runb;
        const int e  = bid;
        const int w  = tid >> 6;
        const int ln = tid & 63;
        const unsigned long long below = (ln == 63) ? ~0ull >> 1
                                                    : (1ull << ln) - 1;
        int* dst = rowlist + e * NROWS;
        if (tid == 0) runb = 0;
        __syncthreads();
        for (int it = 0; it < NROWS / 1024; ++it) {
            int rbase = it * 1024 + tid * 4;
            u32x4 ga = *(const u32x4*)&groups[rbase * 2];      // rows +0,+1
            u32x4 gb = *(const u32x4*)&groups[rbase * 2 + 4];  // rows +2,+3
            bool h0 = ((int)ga.x == e), h1 = ((int)ga.z == e);
            bool h2 = ((int)gb.x == e), h3 = ((int)gb.z == e);
            unsigned long long m0 = __ballot(h0), m1 = __ballot(h1);
            unsigned long long m2 = __ballot(h2), m3 = __ballot(h3);
            int c0 = __popcll(m0), c1 = __popcll(m1), c2 = __popcll(m2);
            if (ln == 0) wcnt_s[w] = c0 + c1 + c2 + __popcll(m3);
            __syncthreads();
            if (tid == 0) {
                int s = runb;
                #pragma unroll
                for (int i = 0; i < 4; ++i) { woff_s[i] = s; s += wcnt_s[i]; }
                runb = s;
            }
            __syncthreads();
            int base = woff_s[w];
            if (h0) dst[base + __popcll(m0 & below)] = rbase;
            if (h1) dst[base + c0 + __popcll(m1 & below)] = rbase + 1;
            if (h2) dst[base + c0 + c1 + __popcll(m2 & below)] = rbase + 2;
            if (h3) dst[base + c0 + c1 + c2 + __popcll(m3 & below)] = rbase + 3;
            __syncthreads();
        }
        if (tid == 0) counts[e] = runb;
    } else if (bid < 1032) {
        // ---- W-tile build (R3-verified layout)
        __shared__ __align__(16) unsigned short tl4[32 * 64];  // 4KB
        const int tb   = bid - 8;
        const int tile = tb >> 2;         // e*32 + nt*8 + kt
        const int qq   = tb & 3;
        const int e  = tile >> 5;
        const int nt = (tile >> 3) & 3;
        const int kt = tile & 7;
        const float* Wb = W + (size_t)e * (KDIM * NDIM);

        const int n   = qq * 32 + (tid & 31);
        const int g   = tid >> 5;               // 0..7
        const int col = nt * BN + n;
        unsigned int p[4];
        #pragma unroll
        for (int jj = 0; jj < 4; ++jj) {
            int k0 = kt * BK + g * 8 + jj * 2;
            unsigned int lo = f2bf_u(Wb[(size_t)k0 * NDIM + col]);
            unsigned int hi = f2bf_u(Wb[(size_t)(k0 + 1) * NDIM + col]);
            p[jj] = lo | (hi << 16);
        }
        *(u32x4*)&tl4[(n & 31) * 64 + (g ^ (n & 7)) * 8] = *(const u32x4*)p;
        __syncthreads();
        unsigned short* dst = Wtile + (size_t)tile * TILE_ELEMS
                                    + ((size_t)qq * 256 + tid) * 8;
        *(u32x4*)dst = *(const u32x4*)&tl4[tid * 8];
    } else {
        // ---- x -> bf16 convert (16 elems/thread, fully coalesced)
        const size_t base = ((size_t)(bid - 1032) * 256 + tid) * 16;
        f32x4 v0 = *(const f32x4*)&x[base];
        f32x4 v1 = *(const f32x4*)&x[base + 4];
        f32x4 v2 = *(const f32x4*)&x[base + 8];
        f32x4 v3 = *(const f32x4*)&x[base + 12];
        *(bf16x8*)&xg[base]     = pack_bf8(v0, v1);
        *(bf16x8*)&xg[base + 8] = pack_bf8(v2, v3);
    }
}

// ---------------- gemm ----------------
// Block = (e = bid&7 -> XCD pin; j = bid>>3: nt = j&3 fastest, mt = j>>2).
// 4 waves; wave w owns rows [w*32, w*32+32) (mi=0,1 sub-tiles) x 128 cols.
// B: 4-deep LDS pipeline, global_load_lds staged 3-ahead, counted vmcnt(12)
//    + raw s_barrier (never drains to 0 in the main loop).
// A: per-lane register gather, lane(q,l15): rows wm+mi*16+l15, 16B chunks at
//    k = kt*64 + h*32 + q*8 — bf16 direct from xg, or f32+pack fallback.

#define STAGE_B(KT, BUF)                                                     \
    {                                                                        \
        const unsigned short* _src = wt + (size_t)(KT) * TILE_ELEMS;         \
        _Pragma("unroll")                                                    \
        for (int _i = 0; _i < 4; ++_i) {                                     \
            int _off = (_i * 256 + tid) * 8;                                 \
            gl_lds16(_src + _off, &Bsm[BUF][_off]);                          \
        }                                                                    \
    }

#define LOAD_A_XG(KT, AR)                                                    \
    {                                                                        \
        const unsigned short* _p0 = arow0 + (KT) * BK + q * 8;               \
        const unsigned short* _p1 = arow1 + (KT) * BK + q * 8;               \
        AR[0][0] = *(const bf16x8*)_p0;                                      \
        AR[0][1] = *(const bf16x8*)(_p0 + 32);                               \
        AR[1][0] = *(const bf16x8*)_p1;                                      \
        AR[1][1] = *(const bf16x8*)(_p1 + 32);                               \
    }

#define LOAD_A_F32(KT, AR)                                                   \
    {                                                                        \
        const float* _p0 = afrow0 + (KT) * BK + q * 8;                       \
        const float* _p1 = afrow1 + (KT) * BK + q * 8;                       \
        AR[0][0] = pack_bf8(*(const f32x4*)_p0, *(const f32x4*)(_p0 + 4));   \
        AR[0][1] = pack_bf8(*(const f32x4*)(_p0 + 32),                       \
                            *(const f32x4*)(_p0 + 36));                      \
        AR[1][0] = pack_bf8(*(const f32x4*)_p1, *(const f32x4*)(_p1 + 4));   \
        AR[1][1] = pack_bf8(*(const f32x4*)(_p1 + 32),                       \
                            *(const f32x4*)(_p1 + 36));                      \
    }

#define COMPUTE(BUF, AR)                                                     \
    {                                                                        \
        _Pragma("unroll")                                                    \
        for (int _h = 0; _h < 2; ++_h) {                                     \
            _Pragma("unroll")                                                \
            for (int _ni = 0; _ni < 8; ++_ni) {                              \
                int _n = _ni * 16 + l15;                                     \
                bf16x8 _bf = *(const bf16x8*)&Bsm[BUF][_n * 64 +             \
                             ((_h * 4 + q) ^ (_n & 7)) * 8];                 \
                acc[0][_ni] = __builtin_amdgcn_mfma_f32_16x16x32_bf16(       \
                    AR[0][_h], _bf, acc[0][_ni], 0, 0, 0);                   \
                acc[1][_ni] = __builtin_amdgcn_mfma_f32_16x16x32_bf16(       \
                    AR[1][_h], _bf, acc[1][_ni], 0, 0, 0);                   \
            }                                                                \
        }                                                                    \
    }

// vmcnt(12) safety: >=12 vmem ops are always issued after B(KT) before this
// wait (3-ahead staging + per-step A loads); in-order vmcnt retirement =>
// B(KT) complete for this wave; s_barrier extends to all waves.
#define KSTEP(KT, ACUR, ANXT, LOADA)                                         \
    {                                                                        \
        asm volatile("s_waitcnt vmcnt(12)" ::: "memory");                    \
        __builtin_amdgcn_s_barrier();                                        \
        __builtin_amdgcn_sched_barrier(0);                                   \
        if ((KT) + 3 < KT_PER) STAGE_B((KT) + 3, ((KT) + 3) & 3)             \
        if ((KT) + 1 < KT_PER) LOADA((KT) + 1, ANXT)                         \
        __builtin_amdgcn_s_setprio(1);                                       \
        COMPUTE((KT) & 3, ACUR)                                              \
        __builtin_amdgcn_s_setprio(0);                                       \
    }

__global__ __launch_bounds__(256, 2)
void gemm_kernel(const float* __restrict__ x,
                 const unsigned short* __restrict__ xg,
                 const int* __restrict__ counts,
                 const int* __restrict__ rowlist,
                 const unsigned short* __restrict__ Wtile,
                 const float* __restrict__ bias,
                 float* __restrict__ out) {
    __shared__ __align__(16) unsigned short Bsm[4][TILE_ELEMS];  // 64KB

    const int bid = blockIdx.x;
    const int e   = bid & 7;
    const int j   = bid >> 3;
    const int nt  = j & 3;
    const int mt  = j >> 2;
    const int cnt = counts[e];
    const int rb  = mt * BM;
    if (rb >= cnt) return;
    int m_valid = cnt - rb;
    if (m_valid > BM) m_valid = BM;
    const int* rl = rowlist + e * NROWS + rb;

    const int tid = threadIdx.x;
    const int w   = tid >> 6;
    const int ln  = tid & 63;
    const int q   = ln >> 4;
    const int l15 = ln & 15;
    const int wm  = w * 32;

    const int r0i = wm + l15;
    const int r1i = wm + 16 + l15;
    const int ri0 = (r0i < m_valid) ? r0i : 0;
    const int ri1 = (r1i < m_valid) ? r1i : 0;

    const unsigned short* wt =
        Wtile + (size_t)((e * NT_PER + nt) * KT_PER) * TILE_ELEMS;

    f32x4 acc[2][8];
    #pragma unroll
    for (int mi = 0; mi < 2; ++mi)
        #pragma unroll
        for (int ni = 0; ni < 8; ++ni)
            acc[mi][ni] = (f32x4){0.f, 0.f, 0.f, 0.f};

    bf16x8 aA[2][2], aB[2][2];

    // prologue: B(0..2) in flight, A(0) in flight
    STAGE_B(0, 0)
    STAGE_B(1, 1)
    STAGE_B(2, 2)

    if (xg != nullptr) {
        const unsigned short* arow0 = xg + (size_t)rl[ri0] * KDIM;
        const unsigned short* arow1 = xg + (size_t)rl[ri1] * KDIM;
        LOAD_A_XG(0, aA)
        KSTEP(0, aA, aB, LOAD_A_XG)
        KSTEP(1, aB, aA, LOAD_A_XG)
        KSTEP(2, aA, aB, LOAD_A_XG)
        KSTEP(3, aB, aA, LOAD_A_XG)
        KSTEP(4, aA, aB, LOAD_A_XG)
        KSTEP(5, aB, aA, LOAD_A_XG)
        KSTEP(6, aA, aB, LOAD_A_XG)
        KSTEP(7, aB, aA, LOAD_A_XG)
    } else {
        const float* afrow0 = x + (size_t)rl[ri0] * KDIM;
        const float* afrow1 = x + (size_t)rl[ri1] * KDIM;
        LOAD_A_F32(0, aA)
        KSTEP(0, aA, aB, LOAD_A_F32)
        KSTEP(1, aB, aA, LOAD_A_F32)
        KSTEP(2, aA, aB, LOAD_A_F32)
        KSTEP(3, aB, aA, LOAD_A_F32)
        KSTEP(4, aA, aB, LOAD_A_F32)
        KSTEP(5, aB, aA, LOAD_A_F32)
        KSTEP(6, aA, aB, LOAD_A_F32)
        KSTEP(7, aB, aA, LOAD_A_F32)
    }

    // ---- epilogue: +bias, masked nontemporal scatter (C/D: col=l15, row=q*4+r)
    int grow[2][4];
    #pragma unroll
    for (int mi = 0; mi < 2; ++mi)
        #pragma unroll
        for (int r = 0; r < 4; ++r) {
            int mloc = wm + mi * 16 + q * 4 + r;
            grow[mi][r] = (mloc < m_valid) ? rl[mloc] : -1;
        }
    const int ncol0 = nt * BN;
    #pragma unroll
    for (int ni = 0; ni < 8; ++ni) {
        int col = ncol0 + ni * 16 + l15;
        float bv = bias[e * NDIM + col];
        #pragma unroll
        for (int mi = 0; mi < 2; ++mi)
            #pragma unroll
            for (int r = 0; r < 4; ++r)
                if (grow[mi][r] >= 0)
                    __builtin_nontemporal_store(acc[mi][ni][r] + bv,
                        &out[(size_t)grow[mi][r] * NDIM + col]);
    }
}

extern "C" void kernel_launch(void* const* d_in, const int* in_sizes, int n_in,
                              void* d_out, int out_size, void* d_ws, size_t ws_size,
                              hipStream_t stream) {
    const float* x      = (const float*)d_in[0];   // (16384, 512) f32
    const int*   groups = (const int*)d_in[1];     // (16384, 2) i32
    const float* W      = (const float*)d_in[2];   // (8, 512, 512) f32
    const float* b      = (const float*)d_in[3];   // (8, 512) f32
    float*       out    = (float*)d_out;           // (16384, 512) f32

    char* ws = (char*)d_ws;
    int*            counts  = (int*)ws;
    int*            rowlist = (int*)(ws + WS_ROWLIST_OFF);
    unsigned short* Wtile   = (unsigned short*)(ws + WS_WT_OFF);
    const bool use_xg = (ws_size >= WS_NEEDED);
    unsigned short* xg = use_xg ? (unsigned short*)(ws + WS_XG_OFF) : nullptr;

    // scatter(8, atomic-free; writes counts) + Wtile(1024) + xconv(2048)
    prep_kernel<<<use_xg ? 3080 : 1032, 256, 0, stream>>>(
        W, x, groups, counts, rowlist, Wtile, xg);
    // 8 e x 128 mt x 4 nt; inactive blocks exit on counts[e].
    // Active ~512 = 2 blocks/CU (LDS-capped), XCD-pinned via bid&7.
    gemm_kernel<<<4096, 256, 0, stream>>>(x, xg, counts, rowlist, Wtile, b, out);
}

// Round 4
// 128.708 us; speedup vs baseline: 1.0288x; 1.0288x over previous
//
#include <hip/hip_runtime.h>
#include <hip/hip_bf16.h>

// SubnetGate = gathered grouped GEMM (B=16384, K=512, N=512, E=8, col 0).
// R6 = R4 (last passing) + two analyzed deltas. R5 (512-thr gemm, vmcnt(8),
// 1024-thr prep, all at once) aborted -> reverted wholesale.
//  - gemm: A-prefetch depth 2 (aA/aB/aC rotation). R4's implicit pre-MFMA
//    wait was vmcnt(4) (A loaded 1 step ahead, after the B stage in queue):
//    the per-step A-gather latency was the stall. Now A issues FIRST in each
//    step and 2 steps ahead -> implicit wait vmcnt(12), full extra step of
//    slack. Explicit per-step vmcnt literals re-derived by region counting
//    (each standalone-guarantees B(kt) retired, incl. tail): see KSTEP table.
//  - prep: scatter 8 rows/thread -> 8 serial ballot iterations (was 16).
//    Bucket order is arbitrary, so compaction order can interleave.
//
// ws layout:
//   [0,      32)       int counts[8]
//   [4096,   528384)   int rowlist[8][16384]
//   [528384, 4722688)  ushort Wtile[8][4 nt][8 kt][128n x 64k bf16, swizzled]
//   [4722688, 21499904) ushort xg[16384][512]   (bf16 copy of x, optional)

#define NROWS   16384
#define KDIM    512
#define NDIM    512
#define NEXP    8
#define BM      128
#define BN      128
#define BK      64
#define NT_PER  4
#define KT_PER  8
#define TILE_ELEMS (BN * BK)          // 8192 bf16 = 16KB
#define WS_ROWLIST_OFF 4096
#define WS_WT_OFF      (4096 + NEXP * NROWS * 4)
#define WS_XG_OFF      (WS_WT_OFF + (size_t)NEXP * NT_PER * KT_PER * TILE_ELEMS * 2)
#define WS_NEEDED      (WS_XG_OFF + (size_t)NROWS * KDIM * 2)

typedef __bf16        bf16x8 __attribute__((ext_vector_type(8)));
typedef float         f32x4  __attribute__((ext_vector_type(4)));
typedef unsigned int  u32x4  __attribute__((ext_vector_type(4)));

__device__ __forceinline__ unsigned int f2bf_u(float f) {
    unsigned int u = __builtin_bit_cast(unsigned int, f);
    return (u + 0x7FFFu + ((u >> 16) & 1u)) >> 16;   // RNE f32->bf16
}

__device__ __forceinline__ void gl_lds16(const void* g, void* l) {
    __builtin_amdgcn_global_load_lds(
        (const __attribute__((address_space(1))) unsigned int*)g,
        (__attribute__((address_space(3))) unsigned int*)l, 16, 0, 0);
}

__device__ __forceinline__ bf16x8 pack_bf8(f32x4 lo, f32x4 hi) {
    u32x4 w;
    w.x = f2bf_u(lo.x) | (f2bf_u(lo.y) << 16);
    w.y = f2bf_u(lo.z) | (f2bf_u(lo.w) << 16);
    w.z = f2bf_u(hi.x) | (f2bf_u(hi.y) << 16);
    w.w = f2bf_u(hi.z) | (f2bf_u(hi.w) << 16);
    return __builtin_bit_cast(bf16x8, w);
}

// blocks [0,8): scatter -- block e scans all 16384 ids, 8 iters x (256 thr x
//   8 rows), ballot+prefix compaction, zero atomics; counts[e] plain store.
// blocks [8,1032): one quarter (32 n-cols) of a 16KB swizzled B-tile
//   (R3/R4-verified layout: granule (n,g) -> tile byte off n*128+(g^(n&7))*16).
// blocks [1032,3080): x f32->bf16 convert into xg (16 elems/thread).
__global__ void prep_kernel(const float* __restrict__ W,
                            const float* __restrict__ x,
                            const int* __restrict__ groups,
                            int* __restrict__ counts,
                            int* __restrict__ rowlist,
                            unsigned short* __restrict__ Wtile,
                            unsigned short* __restrict__ xg) {
    const int bid = blockIdx.x;
    const int tid = threadIdx.x;

    if (bid < 8) {
        __shared__ int wcnt_s[4];
        __shared__ int woff_s[4];
        __shared__ int runb;
        const int e  = bid;
        const int w  = tid >> 6;
        const int ln = tid & 63;
        const unsigned long long below = (ln == 63) ? ~0ull >> 1
                                                    : (1ull << ln) - 1;
        int* dst = rowlist + e * NROWS;
        if (tid == 0) runb = 0;
        __syncthreads();
        for (int it = 0; it < NROWS / 2048; ++it) {      // 8 iterations
            int rbase = it * 2048 + tid * 8;
            u32x4 g0 = *(const u32x4*)&groups[rbase * 2];       // rows +0,+1
            u32x4 g1 = *(const u32x4*)&groups[rbase * 2 + 4];   // rows +2,+3
            u32x4 g2 = *(const u32x4*)&groups[rbase * 2 + 8];   // rows +4,+5
            u32x4 g3 = *(const u32x4*)&groups[rbase * 2 + 12];  // rows +6,+7
            bool h[8] = {(int)g0.x == e, (int)g0.z == e,
                         (int)g1.x == e, (int)g1.z == e,
                         (int)g2.x == e, (int)g2.z == e,
                         (int)g3.x == e, (int)g3.z == e};
            unsigned long long m[8];
            int c[8], tot = 0;
            #pragma unroll
            for (int jj = 0; jj < 8; ++jj) {
                m[jj] = __ballot(h[jj]);
                c[jj] = __popcll(m[jj]);
                tot += c[jj];
            }
            if (ln == 0) wcnt_s[w] = tot;
            __syncthreads();
            if (tid == 0) {
                int s = runb;
                #pragma unroll
                for (int i = 0; i < 4; ++i) { woff_s[i] = s; s += wcnt_s[i]; }
                runb = s;
            }
            __syncthreads();
            int base = woff_s[w];
            #pragma unroll
            for (int jj = 0; jj < 8; ++jj) {
                if (h[jj]) dst[base + __popcll(m[jj] & below)] = rbase + jj;
                base += c[jj];
            }
            __syncthreads();
        }
        if (tid == 0) counts[e] = runb;
    } else if (bid < 1032) {
        // ---- W-tile build (R3/R4-verified layout), quarter-tile per block
        __shared__ __align__(16) unsigned short tl4[32 * 64];  // 4KB
        const int tb   = bid - 8;
        const int tile = tb >> 2;         // e*32 + nt*8 + kt
        const int qq   = tb & 3;
        const int e  = tile >> 5;
        const int nt = (tile >> 3) & 3;
        const int kt = tile & 7;
        const float* Wb = W + (size_t)e * (KDIM * NDIM);

        const int n   = qq * 32 + (tid & 31);
        const int g   = tid >> 5;               // 0..7
        const int col = nt * BN + n;
        unsigned int p[4];
        #pragma unroll
        for (int jj = 0; jj < 4; ++jj) {
            int k0 = kt * BK + g * 8 + jj * 2;
            unsigned int lo = f2bf_u(Wb[(size_t)k0 * NDIM + col]);
            unsigned int hi = f2bf_u(Wb[(size_t)(k0 + 1) * NDIM + col]);
            p[jj] = lo | (hi << 16);
        }
        *(u32x4*)&tl4[(n & 31) * 64 + (g ^ (n & 7)) * 8] = *(const u32x4*)p;
        __syncthreads();
        unsigned short* dst = Wtile + (size_t)tile * TILE_ELEMS
                                    + ((size_t)qq * 256 + tid) * 8;
        *(u32x4*)dst = *(const u32x4*)&tl4[tid * 8];
    } else {
        // ---- x -> bf16 convert (16 elems/thread, fully coalesced)
        const size_t base = ((size_t)(bid - 1032) * 256 + tid) * 16;
        f32x4 v0 = *(const f32x4*)&x[base];
        f32x4 v1 = *(const f32x4*)&x[base + 4];
        f32x4 v2 = *(const f32x4*)&x[base + 8];
        f32x4 v3 = *(const f32x4*)&x[base + 12];
        *(bf16x8*)&xg[base]     = pack_bf8(v0, v1);
        *(bf16x8*)&xg[base + 8] = pack_bf8(v2, v3);
    }
}

// ---------------- gemm ----------------
// Block = (e = bid&7 -> XCD pin; j = bid>>3: nt = j&3 fastest, mt = j>>2).
// 4 waves; wave w owns rows [w*32, w*32+32) (mi=0,1) x 128 cols.
// B: 4-deep LDS pipeline, global_load_lds staged 3-ahead.
// A: per-lane register gather, 2 STEPS AHEAD (aA/aB/aC rotation), issued
//    BEFORE the B stage each step (in-order vmcnt retirement: earlier queue
//    position = earlier retire). Implicit pre-MFMA wait is now vmcnt(12)
//    (was 4 in R4) -- the A-latency stall gets a full step of slack.
// Per-step explicit vmcnt literal VM = #vmem ops issued after B(kt)'s last
// op (region count, issue order: prologue B0,B1,B2,A0,A1; step j issues
// A(j+2) then B(j+3), 4 ops each):
//   kt: 0->16, 1->20, 2->24, 3->16, 4->16, 5->16, 6->12, 7->4.
// If any B(kt) op is outstanding, outstanding > VM -> wait retires it (in
// order); barrier extends to all waves. Never drains to 0 mid-loop.

#define STAGE_B(KT, BUF)                                                     \
    {                                                                        \
        const unsigned short* _src = wt + (size_t)(KT) * TILE_ELEMS;         \
        _Pragma("unroll")                                                    \
        for (int _i = 0; _i < 4; ++_i) {                                     \
            int _off = (_i * 256 + tid) * 8;                                 \
            gl_lds16(_src + _off, &Bsm[BUF][_off]);                          \
        }                                                                    \
    }

#define LOAD_A_XG(KT, AR)                                                    \
    {                                                                        \
        const unsigned short* _p0 = arow0 + (KT) * BK + q * 8;               \
        const unsigned short* _p1 = arow1 + (KT) * BK + q * 8;               \
        AR[0][0] = *(const bf16x8*)_p0;                                      \
        AR[0][1] = *(const bf16x8*)(_p0 + 32);                               \
        AR[1][0] = *(const bf16x8*)_p1;                                      \
        AR[1][1] = *(const bf16x8*)(_p1 + 32);                               \
    }

#define LOAD_A_F32(KT, AR)                                                   \
    {                                                                        \
        const float* _p0 = afrow0 + (KT) * BK + q * 8;                       \
        const float* _p1 = afrow1 + (KT) * BK + q * 8;                       \
        AR[0][0] = pack_bf8(*(const f32x4*)_p0, *(const f32x4*)(_p0 + 4));   \
        AR[0][1] = pack_bf8(*(const f32x4*)(_p0 + 32),                       \
                            *(const f32x4*)(_p0 + 36));                      \
        AR[1][0] = pack_bf8(*(const f32x4*)_p1, *(const f32x4*)(_p1 + 4));   \
        AR[1][1] = pack_bf8(*(const f32x4*)(_p1 + 32),                       \
                            *(const f32x4*)(_p1 + 36));                      \
    }

#define COMPUTE(BUF, AR)                                                     \
    {                                                                        \
        _Pragma("unroll")                                                    \
        for (int _h = 0; _h < 2; ++_h) {                                     \
            _Pragma("unroll")                                                \
            for (int _ni = 0; _ni < 8; ++_ni) {                              \
                int _n = _ni * 16 + l15;                                     \
                bf16x8 _bf = *(const bf16x8*)&Bsm[BUF][_n * 64 +             \
                             ((_h * 4 + q) ^ (_n & 7)) * 8];                 \
                acc[0][_ni] = __builtin_amdgcn_mfma_f32_16x16x32_bf16(       \
                    AR[0][_h], _bf, acc[0][_ni], 0, 0, 0);                   \
                acc[1][_ni] = __builtin_amdgcn_mfma_f32_16x16x32_bf16(       \
                    AR[1][_h], _bf, acc[1][_ni], 0, 0, 0);                   \
            }                                                                \
        }                                                                    \
    }

#define KSTEP(KT, VM, ACUR, ANXT, LOADA)                                     \
    {                                                                        \
        asm volatile("s_waitcnt vmcnt(" #VM ")" ::: "memory");               \
        __builtin_amdgcn_s_barrier();                                        \
        __builtin_amdgcn_sched_barrier(0);                                   \
        if ((KT) + 2 < KT_PER) LOADA((KT) + 2, ANXT)                         \
        if ((KT) + 3 < KT_PER) STAGE_B((KT) + 3, ((KT) + 3) & 3)             \
        __builtin_amdgcn_s_setprio(1);                                       \
        COMPUTE((KT) & 3, ACUR)                                              \
        __builtin_amdgcn_s_setprio(0);                                       \
    }

#define KLOOP(LOADA)                                                         \
    {                                                                        \
        LOADA(0, aA)                                                         \
        LOADA(1, aB)                                                         \
        KSTEP(0, 16, aA, aC, LOADA)                                          \
        KSTEP(1, 20, aB, aA, LOADA)                                          \
        KSTEP(2, 24, aC, aB, LOADA)                                          \
        KSTEP(3, 16, aA, aC, LOADA)                                          \
        KSTEP(4, 16, aB, aA, LOADA)                                          \
        KSTEP(5, 16, aC, aB, LOADA)                                          \
        KSTEP(6, 12, aA, aC, LOADA)                                          \
        KSTEP(7, 4,  aB, aA, LOADA)                                          \
    }

__global__ __launch_bounds__(256, 2)
void gemm_kernel(const float* __restrict__ x,
                 const unsigned short* __restrict__ xg,
                 const int* __restrict__ counts,
                 const int* __restrict__ rowlist,
                 const unsigned short* __restrict__ Wtile,
                 const float* __restrict__ bias,
                 float* __restrict__ out) {
    __shared__ __align__(16) unsigned short Bsm[4][TILE_ELEMS];  // 64KB

    const int bid = blockIdx.x;
    const int e   = bid & 7;
    const int j   = bid >> 3;
    const int nt  = j & 3;
    const int mt  = j >> 2;
    const int cnt = counts[e];
    const int rb  = mt * BM;
    if (rb >= cnt) return;
    int m_valid = cnt - rb;
    if (m_valid > BM) m_valid = BM;
    const int* rl = rowlist + e * NROWS + rb;

    const int tid = threadIdx.x;
    const int w   = tid >> 6;
    const int ln  = tid & 63;
    const int q   = ln >> 4;
    const int l15 = ln & 15;
    const int wm  = w * 32;

    const int r0i = wm + l15;
    const int r1i = wm + 16 + l15;
    const int ri0 = (r0i < m_valid) ? r0i : 0;
    const int ri1 = (r1i < m_valid) ? r1i : 0;

    const unsigned short* wt =
        Wtile + (size_t)((e * NT_PER + nt) * KT_PER) * TILE_ELEMS;

    f32x4 acc[2][8];
    #pragma unroll
    for (int mi = 0; mi < 2; ++mi)
        #pragma unroll
        for (int ni = 0; ni < 8; ++ni)
            acc[mi][ni] = (f32x4){0.f, 0.f, 0.f, 0.f};

    bf16x8 aA[2][2], aB[2][2], aC[2][2];

    // prologue: B(0..2) in flight, then A(0),A(1) (inside KLOOP)
    STAGE_B(0, 0)
    STAGE_B(1, 1)
    STAGE_B(2, 2)

    if (xg != nullptr) {
        const unsigned short* arow0 = xg + (size_t)rl[ri0] * KDIM;
        const unsigned short* arow1 = xg + (size_t)rl[ri1] * KDIM;
        KLOOP(LOAD_A_XG)
    } else {
        const float* afrow0 = x + (size_t)rl[ri0] * KDIM;
        const float* afrow1 = x + (size_t)rl[ri1] * KDIM;
        KLOOP(LOAD_A_F32)
    }

    // ---- epilogue: +bias, masked nontemporal scatter (C/D: col=l15, row=q*4+r)
    int grow[2][4];
    #pragma unroll
    for (int mi = 0; mi < 2; ++mi)
        #pragma unroll
        for (int r = 0; r < 4; ++r) {
            int mloc = wm + mi * 16 + q * 4 + r;
            grow[mi][r] = (mloc < m_valid) ? rl[mloc] : -1;
        }
    const int ncol0 = nt * BN;
    #pragma unroll
    for (int ni = 0; ni < 8; ++ni) {
        int col = ncol0 + ni * 16 + l15;
        float bv = bias[e * NDIM + col];
        #pragma unroll
        for (int mi = 0; mi < 2; ++mi)
            #pragma unroll
            for (int r = 0; r < 4; ++r)
                if (grow[mi][r] >= 0)
                    __builtin_nontemporal_store(acc[mi][ni][r] + bv,
                        &out[(size_t)grow[mi][r] * NDIM + col]);
    }
}

extern "C" void kernel_launch(void* const* d_in, const int* in_sizes, int n_in,
                              void* d_out, int out_size, void* d_ws, size_t ws_size,
                              hipStream_t stream) {
    const float* x      = (const float*)d_in[0];   // (16384, 512) f32
    const int*   groups = (const int*)d_in[1];     // (16384, 2) i32
    const float* W      = (const float*)d_in[2];   // (8, 512, 512) f32
    const float* b      = (const float*)d_in[3];   // (8, 512) f32
    float*       out    = (float*)d_out;           // (16384, 512) f32

    char* ws = (char*)d_ws;
    int*            counts  = (int*)ws;
    int*            rowlist = (int*)(ws + WS_ROWLIST_OFF);
    unsigned short* Wtile   = (unsigned short*)(ws + WS_WT_OFF);
    const bool use_xg = (ws_size >= WS_NEEDED);
    unsigned short* xg = use_xg ? (unsigned short*)(ws + WS_XG_OFF) : nullptr;

    // scatter(8) + Wtile(1024) + xconv(2048), 256 threads/block
    prep_kernel<<<use_xg ? 3080 : 1032, 256, 0, stream>>>(
        W, x, groups, counts, rowlist, Wtile, xg);
    // 8 e x 128 mt x 4 nt; inactive blocks exit on counts[e].
    // Active ~512 = 2 blocks/CU, XCD-pinned via bid&7.
    gemm_kernel<<<4096, 256, 0, stream>>>(x, xg, counts, rowlist, Wtile, b, out);
}